// Round 1
// baseline (264.677 us; speedup 1.0000x reference)
//
#include <hip/hip_runtime.h>

#define BATCH 256
#define QN 64
#define HN 2048
#define H4 (HN / 4)   // 512

// Kernel A: factor[k][h] = prod_{j>k} W[k][j][h] * prod_{i<k} W[i][k][h]
// One thread per (k, h4) -> QN * H4 = 32768 threads. All loads coalesced in h.
__global__ __launch_bounds__(256) void factor_kernel(const float* __restrict__ W,
                                                     float* __restrict__ factor) {
    int idx = blockIdx.x * blockDim.x + threadIdx.x;   // 0..32767
    int h4 = idx & (H4 - 1);
    int k  = idx >> 9;                                 // idx / 512
    const float4* W4 = (const float4*)W;
    float4 p = make_float4(1.f, 1.f, 1.f, 1.f);
    for (int j = k + 1; j < QN; ++j) {
        float4 w = W4[(k * QN + j) * H4 + h4];
        p.x *= w.x; p.y *= w.y; p.z *= w.z; p.w *= w.w;
    }
    for (int i = 0; i < k; ++i) {
        float4 w = W4[(i * QN + k) * H4 + h4];
        p.x *= w.x; p.y *= w.y; p.z *= w.z; p.w *= w.w;
    }
    ((float4*)factor)[k * H4 + h4] = p;
}

// Kernel B: per (b,q) row of H=2048: y = x * factor[q], out = y / max(||y||, eps)
// One 256-thread block per row; each thread handles 2 float4 (8 floats).
__global__ __launch_bounds__(256) void normalize_kernel(const float* __restrict__ x,
                                                        const float* __restrict__ factor,
                                                        float* __restrict__ out) {
    const int row = blockIdx.x;            // 0 .. BATCH*QN-1
    const int q   = row & (QN - 1);
    const int t   = threadIdx.x;

    const float4* x4 = (const float4*)(x + (size_t)row * HN);
    const float4* f4 = (const float4*)(factor + (size_t)q * HN);
    float4*       o4 = (float4*)(out + (size_t)row * HN);

    float4 a0 = x4[t];
    float4 a1 = x4[t + 256];
    float4 b0 = f4[t];
    float4 b1 = f4[t + 256];

    float4 y0, y1;
    y0.x = a0.x * b0.x; y0.y = a0.y * b0.y; y0.z = a0.z * b0.z; y0.w = a0.w * b0.w;
    y1.x = a1.x * b1.x; y1.y = a1.y * b1.y; y1.z = a1.z * b1.z; y1.w = a1.w * b1.w;

    float ss = y0.x * y0.x + y0.y * y0.y + y0.z * y0.z + y0.w * y0.w
             + y1.x * y1.x + y1.y * y1.y + y1.z * y1.z + y1.w * y1.w;

    // wave-64 butterfly-free down-shuffle reduce
    #pragma unroll
    for (int off = 32; off >= 1; off >>= 1)
        ss += __shfl_down(ss, off, 64);

    __shared__ float wsum[4];
    if ((t & 63) == 0) wsum[t >> 6] = ss;
    __syncthreads();
    float total = wsum[0] + wsum[1] + wsum[2] + wsum[3];

    float inv = 1.0f / fmaxf(sqrtf(total), 1e-12f);

    y0.x *= inv; y0.y *= inv; y0.z *= inv; y0.w *= inv;
    y1.x *= inv; y1.y *= inv; y1.z *= inv; y1.w *= inv;

    o4[t]       = y0;
    o4[t + 256] = y1;
}

extern "C" void kernel_launch(void* const* d_in, const int* in_sizes, int n_in,
                              void* d_out, int out_size, void* d_ws, size_t ws_size,
                              hipStream_t stream) {
    const float* x = (const float*)d_in[0];
    const float* W = (const float*)d_in[1];
    float* out     = (float*)d_out;
    float* factor  = (float*)d_ws;   // QN*HN floats = 512 KB

    factor_kernel<<<(QN * H4) / 256, 256, 0, stream>>>(W, factor);
    normalize_kernel<<<BATCH * QN, 256, 0, stream>>>(x, factor, out);
}

// Round 3
// 247.983 us; speedup vs baseline: 1.0673x; 1.0673x over previous
//
#include <hip/hip_runtime.h>

#define BATCH 256
#define QN 64
#define HN 2048
#define H2 (HN / 2)   // 1024

typedef float v4f __attribute__((ext_vector_type(4)));

// Kernel A: factor[k][h] = prod_{j>k} W[k][j][h] * prod_{i<k} W[i][k][h]
// One thread per (k, h2) -> QN * H2 = 65536 threads = 256 blocks (1 per CU).
__global__ __launch_bounds__(256) void factor_kernel(const float* __restrict__ W,
                                                     float* __restrict__ factor) {
    int idx = blockIdx.x * blockDim.x + threadIdx.x;   // 0..65535
    int h2 = idx & (H2 - 1);
    int k  = idx >> 10;                                // idx / 1024
    const float2* W2 = (const float2*)W;
    float2 p = make_float2(1.f, 1.f);
    #pragma unroll 4
    for (int j = k + 1; j < QN; ++j) {
        float2 w = W2[(size_t)(k * QN + j) * H2 + h2];
        p.x *= w.x; p.y *= w.y;
    }
    #pragma unroll 4
    for (int i = 0; i < k; ++i) {
        float2 w = W2[(size_t)(i * QN + k) * H2 + h2];
        p.x *= w.x; p.y *= w.y;
    }
    ((float2*)factor)[(size_t)k * H2 + h2] = p;
}

// Kernel B: one WAVE per (b,q) row of H=2048 (64 lanes x 8 float4 = 2048 floats).
// Pure shuffle reduction — no LDS, no __syncthreads. Streaming x/out get
// nontemporal hints so the 512 KB factor table stays cache-resident.
__global__ __launch_bounds__(256) void normalize_kernel(const float* __restrict__ x,
                                                        const float* __restrict__ factor,
                                                        float* __restrict__ out) {
    const int row  = blockIdx.x * 4 + (threadIdx.x >> 6);   // 4 waves/block
    const int lane = threadIdx.x & 63;
    const int q    = row & (QN - 1);

    const v4f* x4 = (const v4f*)(x + (size_t)row * HN);
    const v4f* f4 = (const v4f*)(factor + (size_t)q * HN);
    v4f*       o4 = (v4f*)(out + (size_t)row * HN);

    v4f a[8], b[8];
    #pragma unroll
    for (int i = 0; i < 8; ++i)
        a[i] = __builtin_nontemporal_load(&x4[lane + 64 * i]);
    #pragma unroll
    for (int i = 0; i < 8; ++i)
        b[i] = f4[lane + 64 * i];

    float ss = 0.f;
    #pragma unroll
    for (int i = 0; i < 8; ++i) {
        a[i] *= b[i];
        ss += a[i].x * a[i].x + a[i].y * a[i].y + a[i].z * a[i].z + a[i].w * a[i].w;
    }

    // wave-64 butterfly: every lane ends with the full row sum
    #pragma unroll
    for (int off = 32; off >= 1; off >>= 1)
        ss += __shfl_xor(ss, off, 64);

    float inv = 1.0f / fmaxf(sqrtf(ss), 1e-12f);

    #pragma unroll
    for (int i = 0; i < 8; ++i) {
        a[i] *= inv;
        __builtin_nontemporal_store(a[i], &o4[lane + 64 * i]);
    }
}

extern "C" void kernel_launch(void* const* d_in, const int* in_sizes, int n_in,
                              void* d_out, int out_size, void* d_ws, size_t ws_size,
                              hipStream_t stream) {
    const float* x = (const float*)d_in[0];
    const float* W = (const float*)d_in[1];
    float* out     = (float*)d_out;
    float* factor  = (float*)d_ws;   // QN*HN floats = 512 KB

    factor_kernel<<<(QN * H2) / 256, 256, 0, stream>>>(W, factor);
    normalize_kernel<<<(BATCH * QN) / 4, 256, 0, stream>>>(x, factor, out);
}